// Round 4
// baseline (268.397 us; speedup 1.0000x reference)
//
#include <hip/hip_runtime.h>
#include <stdint.h>

#define SEQ  2048
#define DIMC 256
#define HID  512
#define NH   8
#define DH   64

typedef __attribute__((ext_vector_type(8))) short bf16x8;
typedef __attribute__((ext_vector_type(4))) float f32x4;
typedef __attribute__((address_space(1))) const uint32_t guint_t;
typedef __attribute__((address_space(3))) uint32_t luint_t;

// async global->LDS, 16B per lane; LDS dest = wave-uniform base + lane*16
__device__ __forceinline__ void gld16(const void* g, void* l) {
  __builtin_amdgcn_global_load_lds((guint_t*)g, (luint_t*)l, 16, 0, 0);
}

__device__ __forceinline__ unsigned short f2bf(float f) {
  union { float f; uint32_t u; } v; v.f = f;
  return (unsigned short)((v.u + 0x7FFFu + ((v.u >> 16) & 1u)) >> 16);
}

// pack two fp32 -> (bf16,bf16) dword, round-half-up
__device__ __forceinline__ uint32_t pk_bf16(float f0, float f1) {
  union { float f; uint32_t u; } a, b; a.f = f0; b.f = f1;
  return __builtin_amdgcn_perm(b.u + 0x8000u, a.u + 0x8000u, 0x07060302u);
}

// ---------------------------------------------------------------------------
// prep: w_qkv -> bf16 (Q rows pre-scaled by SCALE*log2e), w_out -> bf16,
//       x [b][i][n] fp32 -> xT [b][n][i] bf16
// ---------------------------------------------------------------------------
__global__ __launch_bounds__(256) void prep_kernel(
    const float* __restrict__ x, const float* __restrict__ wqkv,
    const float* __restrict__ wout,
    unsigned short* __restrict__ wqkv_b, unsigned short* __restrict__ wout_b,
    unsigned short* __restrict__ xT) {
  __shared__ float tile[64][65];
  int blk = blockIdx.x;
  int t = threadIdx.x;
  if (blk < 384) {
    int idx = blk * 1024 + t * 4;
    float4 v = *(const float4*)(wqkv + idx);
    float s = ((idx >> 8) < HID) ? 0.18033688011112042f : 1.0f;  // 0.125*log2(e)
    ushort4 o;
    o.x = f2bf(v.x * s); o.y = f2bf(v.y * s);
    o.z = f2bf(v.z * s); o.w = f2bf(v.w * s);
    *(ushort4*)(wqkv_b + idx) = o;
    return;
  }
  if (blk < 512) {
    int idx = (blk - 384) * 1024 + t * 4;
    float4 v = *(const float4*)(wout + idx);
    ushort4 o;
    o.x = f2bf(v.x); o.y = f2bf(v.y); o.z = f2bf(v.z); o.w = f2bf(v.w);
    *(ushort4*)(wout_b + idx) = o;
    return;
  }
  int tid = blk - 512;
  int b  = tid >> 7;
  int r  = tid & 127;
  int i0 = (r >> 5) * 64;
  int n0 = (r & 31) * 64;
  const float* xb = x + (size_t)b * DIMC * SEQ;
  int tn = t & 15, ti = t >> 4;
#pragma unroll
  for (int j = 0; j < 4; j++) {
    int il = ti + j * 16;
    float4 v = *(const float4*)(xb + (size_t)(i0 + il) * SEQ + n0 + tn * 4);
    tile[il][tn*4+0] = v.x; tile[il][tn*4+1] = v.y;
    tile[il][tn*4+2] = v.z; tile[il][tn*4+3] = v.w;
  }
  __syncthreads();
  unsigned short* xTb = xT + (size_t)b * SEQ * DIMC;
#pragma unroll
  for (int j = 0; j < 4; j++) {
    int nl = ti + j * 16;
    int i4 = tn * 4;
    uint2 pk;
    pk.x = (uint32_t)f2bf(tile[i4+0][nl]) | ((uint32_t)f2bf(tile[i4+1][nl]) << 16);
    pk.y = (uint32_t)f2bf(tile[i4+2][nl]) | ((uint32_t)f2bf(tile[i4+3][nl]) << 16);
    *(uint2*)(xTb + (size_t)(n0 + nl) * DIMC + i0 + i4) = pk;
  }
}

// ---------------------------------------------------------------------------
// qkv_gemm: [1536,256]x[256,2048] per batch, 128x128 tile, BK=64.
// global_load_lds (16B) staging into unpadded XOR-swizzled tiles.
// ---------------------------------------------------------------------------
__global__ __launch_bounds__(256, 2) void qkv_gemm(
    const unsigned short* __restrict__ wq, const unsigned short* __restrict__ xT,
    unsigned short* __restrict__ Qs, unsigned short* __restrict__ Ks,
    unsigned short* __restrict__ Vt) {
  __shared__ unsigned short lds[17408];   // staging: la[128*64], lb[128*64]; epilogue 128*136
  unsigned short* la = lds;
  unsigned short* lb = lds + 8192;
  int o0 = blockIdx.x * 128;
  int n0 = blockIdx.y * 128;
  int b  = blockIdx.z;
  int t  = threadIdx.x;
  int wv = t >> 6, l = t & 63, l15 = l & 15, q = l >> 4;
  int wm = (wv & 1) * 64, wn = (wv >> 1) * 64;
  f32x4 acc[4][4];
#pragma unroll
  for (int i = 0; i < 4; i++)
#pragma unroll
    for (int j = 0; j < 4; j++) acc[i][j] = (f32x4){0.f, 0.f, 0.f, 0.f};
  const unsigned short* Ag = wq + (size_t)o0 * DIMC;
  const unsigned short* Bg = xT + ((size_t)b * SEQ + n0) * DIMC;
  int lrow8 = l >> 3, lcol = l & 7;
  for (int kk = 0; kk < 4; kk++) {
    int k0 = kk * 64;
    __syncthreads();
#pragma unroll
    for (int c0 = 0; c0 < 4; c0++) {
      int c = wv * 4 + c0;                   // 16 chunks of 8 rows x 128B
      int row = c * 8 + lrow8;
      int sg = lcol ^ (row & 7);             // permute GLOBAL col; LDS slot = lane&7
      gld16(Ag + (size_t)row * DIMC + k0 + sg * 8, la + c * 512);
      gld16(Bg + (size_t)row * DIMC + k0 + sg * 8, lb + c * 512);
    }
    __syncthreads();
#pragma unroll
    for (int kh = 0; kh < 2; kh++) {
      bf16x8 af[4], bfr[4];
#pragma unroll
      for (int mt = 0; mt < 4; mt++) {
        int row = wm + mt*16 + l15;
        af[mt] = *(const bf16x8*)(la + row*64 + ((kh*4 + q) ^ (row & 7)) * 8);
      }
#pragma unroll
      for (int nt = 0; nt < 4; nt++) {
        int row = wn + nt*16 + l15;
        bfr[nt] = *(const bf16x8*)(lb + row*64 + ((kh*4 + q) ^ (row & 7)) * 8);
      }
#pragma unroll
      for (int mt = 0; mt < 4; mt++)
#pragma unroll
        for (int nt = 0; nt < 4; nt++)
          acc[mt][nt] = __builtin_amdgcn_mfma_f32_16x16x32_bf16(af[mt], bfr[nt], acc[mt][nt], 0, 0, 0);
    }
  }
  __syncthreads();
  int seg3 = o0 >> 9;            // 0=Q, 1=K, 2=V
  int h0   = (o0 & 511) >> 6;
  if (seg3 == 2) {
#pragma unroll
    for (int mt = 0; mt < 4; mt++)
#pragma unroll
      for (int nt = 0; nt < 4; nt++)
#pragma unroll
        for (int r = 0; r < 4; r++) {
          int ol = wm + mt * 16 + q * 4 + r;
          int h = h0 + (ol >> 6), d = ol & 63;
          int n = n0 + wn + nt * 16 + l15;
          Vt[(((size_t)b * NH + h) * DH + d) * SEQ + n] = f2bf(acc[mt][nt][r]);
        }
  } else {
    unsigned short* dst = (seg3 == 0) ? Qs : Ks;
#pragma unroll
    for (int mt = 0; mt < 4; mt++)
#pragma unroll
      for (int nt = 0; nt < 4; nt++)
#pragma unroll
        for (int r = 0; r < 4; r++) {
          int ol = wm + mt * 16 + q * 4 + r;
          int nn = wn + nt * 16 + l15;
          lds[nn * 136 + ol] = f2bf(acc[mt][nt][r]);
        }
    __syncthreads();
#pragma unroll
    for (int i = 0; i < 8; i++) {
      int idx = i * 256 + t;
      int nn  = idx >> 4;
      int olb = (idx & 15) * 8;
      uint4 v = *(const uint4*)(lds + nn * 136 + olb);
      int h = h0 + (olb >> 6), d = olb & 63;
      *(uint4*)(dst + (((size_t)b * NH + h) * SEQ + n0 + nn) * DH + d) = v;
    }
  }
}

// ---------------------------------------------------------------------------
// attn: barrier-free streaming flash, KV-split in-block.
// 512 threads = 8 waves. Waves 0-3: keys [0,1024) for queries qg*32..;
// waves 4-7: keys [1024,2048) for the same queries. M=32 queries/wave keeps
// VGPR<=128 -> 4 waves/SIMD; grid 512 blocks = full residency, zero tail.
// No max-subtraction => partials purely additive => in-LDS combine at end.
// ---------------------------------------------------------------------------
__global__ __launch_bounds__(512, 4) void attn_kernel(
    const unsigned short* __restrict__ Qs, const unsigned short* __restrict__ Ks,
    const unsigned short* __restrict__ Vt, unsigned short* __restrict__ AO) {
  __shared__ unsigned short Ps[8 * 32 * 72];   // per-wave P; reused for combine
  int n0 = blockIdx.x * 128;
  int bh = blockIdx.y;
  int b = bh >> 3, h = bh & 7;
  int t = threadIdx.x;
  int w = t >> 6, l = t & 63, l15 = l & 15, q = l >> 4;
  int cg = w >> 2;          // kv chunk
  int qg = w & 3;           // query group
  const unsigned short* Qg = Qs + ((size_t)bh * SEQ + n0 + qg * 32) * DH;
  bf16x8 qb[2][2];
#pragma unroll
  for (int nt = 0; nt < 2; nt++)
#pragma unroll
    for (int kh = 0; kh < 2; kh++)
      qb[nt][kh] = *(const bf16x8*)(Qg + (nt*16 + l15) * DH + kh*32 + q*8);
  f32x4 oacc[2][4];
  float lrowp[2] = {0.f, 0.f};
#pragma unroll
  for (int nt = 0; nt < 2; nt++)
#pragma unroll
    for (int dt = 0; dt < 4; dt++) oacc[nt][dt] = (f32x4){0.f,0.f,0.f,0.f};
  unsigned short* Pw = Ps + w * 2304;
  const unsigned short* Kg = Ks + (size_t)bh * SEQ * DH;
  const unsigned short* Vg = Vt + (size_t)bh * DH * SEQ;
  for (int tile = 0; tile < 8; tile++) {
    int j0 = cg * 1024 + tile * 128;
#pragma unroll
    for (int half = 0; half < 2; half++) {
      int jb = j0 + half * 64;
      // S^T = K Q^T, 16 keys per jtl; exp2 + packed b64 P write
#pragma unroll
      for (int jtl = 0; jtl < 4; jtl++) {
        const unsigned short* krow = Kg + (size_t)(jb + jtl*16 + l15) * DH;
        bf16x8 kb0 = *(const bf16x8*)(krow + q*8);
        bf16x8 kb1 = *(const bf16x8*)(krow + 32 + q*8);
        f32x4 st[2];
#pragma unroll
        for (int nt = 0; nt < 2; nt++) {
          f32x4 z = (f32x4){0.f,0.f,0.f,0.f};
          z = __builtin_amdgcn_mfma_f32_16x16x32_bf16(kb0, qb[nt][0], z, 0,0,0);
          z = __builtin_amdgcn_mfma_f32_16x16x32_bf16(kb1, qb[nt][1], z, 0,0,0);
          st[nt] = z;
        }
#pragma unroll
        for (int nt = 0; nt < 2; nt++) {
          float p0 = __builtin_amdgcn_exp2f(st[nt][0]);
          float p1 = __builtin_amdgcn_exp2f(st[nt][1]);
          float p2 = __builtin_amdgcn_exp2f(st[nt][2]);
          float p3 = __builtin_amdgcn_exp2f(st[nt][3]);
          lrowp[nt] += (p0 + p1) + (p2 + p3);
          uint2 pk;
          pk.x = pk_bf16(p0, p1);
          pk.y = pk_bf16(p2, p3);
          *(uint2*)(Pw + (nt*16 + l15) * 72 + jtl*16 + q*4) = pk;
        }
      }
      // PV per 32-key column group: V frags from global, P from per-wave LDS
#pragma unroll
      for (int kc = 0; kc < 2; kc++) {
        bf16x8 vb[4];
#pragma unroll
        for (int dt = 0; dt < 4; dt++)
          vb[dt] = *(const bf16x8*)(Vg + (size_t)(dt*16 + l15) * SEQ + jb + kc*32 + q*8);
#pragma unroll
        for (int nt = 0; nt < 2; nt++) {
          bf16x8 pa = *(const bf16x8*)(Pw + (nt*16 + l15) * 72 + kc*32 + q*8);
#pragma unroll
          for (int dt = 0; dt < 4; dt++)
            oacc[nt][dt] = __builtin_amdgcn_mfma_f32_16x16x32_bf16(pa, vb[dt], oacc[nt][dt], 0,0,0);
        }
      }
    }
  }
  // ---- in-block combine of the two kv-chunks ----
  float lred[2];
#pragma unroll
  for (int nt = 0; nt < 2; nt++) {
    float v = lrowp[nt];
    v += __shfl_xor(v, 16);
    v += __shfl_xor(v, 32);
    lred[nt] = v;                // lane holds sum for query nt*16 + l15
  }
  __syncthreads();               // everyone done with P region
  float* Oc = (float*)Ps;                       // 128 q x 64 d fp32 = 32768 B
  float* Lc = (float*)(Ps + 16384);             // byte 32768: 256 floats
  if (cg == 1) {
#pragma unroll
    for (int nt = 0; nt < 2; nt++) {
#pragma unroll
      for (int dt = 0; dt < 4; dt++)
#pragma unroll
        for (int r = 0; r < 4; r++)
          Oc[(qg*32 + nt*16 + q*4 + r) * 64 + dt*16 + l15] = oacc[nt][dt][r];
      if (l < 16) Lc[qg*32 + nt*16 + l15] = lred[nt];
    }
  }
  __syncthreads();
  if (cg == 0) {
    unsigned short* AOb = AO + (size_t)b * SEQ * HID + h * DH;
#pragma unroll
    for (int nt = 0; nt < 2; nt++)
#pragma unroll
      for (int r = 0; r < 4; r++) {
        float lo = __shfl(lred[nt], q*4 + r);
        float lp = Lc[qg*32 + nt*16 + q*4 + r];
        float inv = __builtin_amdgcn_rcpf(lo + lp);
        int n = n0 + qg*32 + nt*16 + q*4 + r;
#pragma unroll
        for (int dt = 0; dt < 4; dt++) {
          float op = Oc[(qg*32 + nt*16 + q*4 + r) * 64 + dt*16 + l15];
          AOb[(size_t)n * HID + dt*16 + l15] = f2bf((oacc[nt][dt][r] + op) * inv);
        }
      }
  }
}

// ---------------------------------------------------------------------------
// out_gemm: [256,512] x AO^T -> out[b][256][2048] fp32 + bias
// global_load_lds staging, XOR-swizzled tiles.
// ---------------------------------------------------------------------------
__global__ __launch_bounds__(256, 2) void out_gemm(
    const unsigned short* __restrict__ wo, const unsigned short* __restrict__ AO,
    const float* __restrict__ bias, float* __restrict__ out) {
  __shared__ unsigned short la[64 * 64];
  __shared__ unsigned short lb[128 * 64];
  int o0 = blockIdx.x * 64;
  int n0 = blockIdx.y * 128;
  int b  = blockIdx.z;
  int t  = threadIdx.x;
  int wv = t >> 6, l = t & 63, l15 = l & 15, q = l >> 4;
  int wm = (wv & 1) * 32, wn = (wv >> 1) * 64;
  f32x4 acc[2][4];
#pragma unroll
  for (int i = 0; i < 2; i++)
#pragma unroll
    for (int j = 0; j < 4; j++) acc[i][j] = (f32x4){0.f,0.f,0.f,0.f};
  const unsigned short* Ag = wo + (size_t)o0 * HID;
  const unsigned short* Bg = AO + ((size_t)b * SEQ + n0) * HID;
  int lrow8 = l >> 3, lcol = l & 7;
  for (int kk = 0; kk < 8; kk++) {
    int k0 = kk * 64;
    __syncthreads();
#pragma unroll
    for (int c0 = 0; c0 < 2; c0++) {       // A: 8 chunks
      int c = wv * 2 + c0;
      int row = c * 8 + lrow8;
      int sg = lcol ^ (row & 7);
      gld16(Ag + (size_t)row * HID + k0 + sg * 8, la + c * 512);
    }
#pragma unroll
    for (int c0 = 0; c0 < 4; c0++) {       // B: 16 chunks
      int c = wv * 4 + c0;
      int row = c * 8 + lrow8;
      int sg = lcol ^ (row & 7);
      gld16(Bg + (size_t)row * HID + k0 + sg * 8, lb + c * 512);
    }
    __syncthreads();
#pragma unroll
    for (int kh = 0; kh < 2; kh++) {
      bf16x8 af[2], bfr[4];
#pragma unroll
      for (int mt = 0; mt < 2; mt++) {
        int row = wm + mt*16 + l15;
        af[mt] = *(const bf16x8*)(la + row*64 + ((kh*4 + q) ^ (row & 7)) * 8);
      }
#pragma unroll
      for (int nt = 0; nt < 4; nt++) {
        int row = wn + nt*16 + l15;
        bfr[nt] = *(const bf16x8*)(lb + row*64 + ((kh*4 + q) ^ (row & 7)) * 8);
      }
#pragma unroll
      for (int mt = 0; mt < 2; mt++)
#pragma unroll
        for (int nt = 0; nt < 4; nt++)
          acc[mt][nt] = __builtin_amdgcn_mfma_f32_16x16x32_bf16(af[mt], bfr[nt], acc[mt][nt], 0,0,0);
    }
  }
#pragma unroll
  for (int mt = 0; mt < 2; mt++)
#pragma unroll
    for (int nt = 0; nt < 4; nt++)
#pragma unroll
      for (int r = 0; r < 4; r++) {
        int o2 = o0 + wm + mt*16 + q*4 + r;
        int n  = n0 + wn + nt*16 + l15;
        out[((size_t)b * DIMC + o2) * SEQ + n] = acc[mt][nt][r] + bias[o2];
      }
}

extern "C" void kernel_launch(void* const* d_in, const int* in_sizes, int n_in,
                              void* d_out, int out_size, void* d_ws, size_t ws_size,
                              hipStream_t stream) {
  const float* x    = (const float*)d_in[0];
  const float* wqkv = (const float*)d_in[1];
  const float* wout = (const float*)d_in[2];
  const float* bout = (const float*)d_in[3];
  float* out = (float*)d_out;
  char* ws = (char*)d_ws;
  unsigned short* wqkv_b = (unsigned short*)(ws);
  unsigned short* wout_b = (unsigned short*)(ws + 786432);
  unsigned short* xT     = (unsigned short*)(ws + 1048576);
  unsigned short* Qs     = (unsigned short*)(ws + 5242880);
  unsigned short* Ks     = (unsigned short*)(ws + 13631488);
  unsigned short* Vt     = (unsigned short*)(ws + 22020096);
  unsigned short* AO     = (unsigned short*)(ws + 30408704);
  prep_kernel<<<1024, 256, 0, stream>>>(x, wqkv, wout, wqkv_b, wout_b, xT);
  qkv_gemm<<<dim3(12, 16, 4), 256, 0, stream>>>(wqkv_b, xT, Qs, Ks, Vt);
  attn_kernel<<<dim3(16, 32), 512, 0, stream>>>(Qs, Ks, Vt, AO);
  out_gemm<<<dim3(4, 16, 4), 256, 0, stream>>>(wout_b, AO, bout, out);
}

// Round 5
// 135.217 us; speedup vs baseline: 1.9849x; 1.9849x over previous
//
#include <hip/hip_runtime.h>
#include <stdint.h>

#define SEQ  2048
#define DIMC 256
#define HID  512
#define NH   8
#define DH   64

typedef __attribute__((ext_vector_type(8))) short bf16x8;
typedef __attribute__((ext_vector_type(4))) float f32x4;
typedef __attribute__((ext_vector_type(16))) float f32x16;
typedef __attribute__((ext_vector_type(2))) unsigned uint2v;
typedef __attribute__((address_space(1))) const uint32_t guint_t;
typedef __attribute__((address_space(3))) uint32_t luint_t;

// async global->LDS, 16B per lane; LDS dest = wave-uniform base + lane*16
__device__ __forceinline__ void gld16(const void* g, void* l) {
  __builtin_amdgcn_global_load_lds((guint_t*)g, (luint_t*)l, 16, 0, 0);
}

__device__ __forceinline__ unsigned short f2bf(float f) {
  union { float f; uint32_t u; } v; v.f = f;
  return (unsigned short)((v.u + 0x7FFFu + ((v.u >> 16) & 1u)) >> 16);
}

__device__ __forceinline__ uint32_t fbits(float f) {
  union { float f; uint32_t u; } v; v.f = f; return v.u;
}

// pack two fp32 (raw bits) -> (bf16,bf16) dword, round-half-up
__device__ __forceinline__ uint32_t pku(uint32_t u0, uint32_t u1) {
  return __builtin_amdgcn_perm(u1 + 0x8000u, u0 + 0x8000u, 0x07060302u);
}

// exchange hi 32 lanes of a with lo 32 lanes of b:
// a' = {a.lo, b.lo}, b' = {a.hi, b.hi}
__device__ __forceinline__ void swap32(uint32_t& a, uint32_t& b) {
#if __has_builtin(__builtin_amdgcn_permlane32_swap)
  uint2v r = __builtin_amdgcn_permlane32_swap(a, b, false, false);
  a = r[0]; b = r[1];
#else
  uint32_t aw = __shfl_xor(a, 32);
  uint32_t bw = __shfl_xor(b, 32);
  bool lo = (threadIdx.x & 32) == 0;
  uint32_t an = lo ? a : bw;
  uint32_t bn = lo ? aw : b;
  a = an; b = bn;
#endif
}

// ---------------------------------------------------------------------------
// prep: w_qkv -> bf16 (Q rows pre-scaled by SCALE*log2e), w_out -> bf16,
//       x [b][i][n] fp32 -> xT [b][n][i] bf16
// ---------------------------------------------------------------------------
__global__ __launch_bounds__(256) void prep_kernel(
    const float* __restrict__ x, const float* __restrict__ wqkv,
    const float* __restrict__ wout,
    unsigned short* __restrict__ wqkv_b, unsigned short* __restrict__ wout_b,
    unsigned short* __restrict__ xT) {
  __shared__ float tile[64][65];
  int blk = blockIdx.x;
  int t = threadIdx.x;
  if (blk < 384) {
    int idx = blk * 1024 + t * 4;
    float4 v = *(const float4*)(wqkv + idx);
    float s = ((idx >> 8) < HID) ? 0.18033688011112042f : 1.0f;  // 0.125*log2(e)
    ushort4 o;
    o.x = f2bf(v.x * s); o.y = f2bf(v.y * s);
    o.z = f2bf(v.z * s); o.w = f2bf(v.w * s);
    *(ushort4*)(wqkv_b + idx) = o;
    return;
  }
  if (blk < 512) {
    int idx = (blk - 384) * 1024 + t * 4;
    float4 v = *(const float4*)(wout + idx);
    ushort4 o;
    o.x = f2bf(v.x); o.y = f2bf(v.y); o.z = f2bf(v.z); o.w = f2bf(v.w);
    *(ushort4*)(wout_b + idx) = o;
    return;
  }
  int tid = blk - 512;
  int b  = tid >> 7;
  int r  = tid & 127;
  int i0 = (r >> 5) * 64;
  int n0 = (r & 31) * 64;
  const float* xb = x + (size_t)b * DIMC * SEQ;
  int tn = t & 15, ti = t >> 4;
#pragma unroll
  for (int j = 0; j < 4; j++) {
    int il = ti + j * 16;
    float4 v = *(const float4*)(xb + (size_t)(i0 + il) * SEQ + n0 + tn * 4);
    tile[il][tn*4+0] = v.x; tile[il][tn*4+1] = v.y;
    tile[il][tn*4+2] = v.z; tile[il][tn*4+3] = v.w;
  }
  __syncthreads();
  unsigned short* xTb = xT + (size_t)b * SEQ * DIMC;
#pragma unroll
  for (int j = 0; j < 4; j++) {
    int nl = ti + j * 16;
    int i4 = tn * 4;
    uint2 pk;
    pk.x = (uint32_t)f2bf(tile[i4+0][nl]) | ((uint32_t)f2bf(tile[i4+1][nl]) << 16);
    pk.y = (uint32_t)f2bf(tile[i4+2][nl]) | ((uint32_t)f2bf(tile[i4+3][nl]) << 16);
    *(uint2*)(xTb + (size_t)(n0 + nl) * DIMC + i0 + i4) = pk;
  }
}

// ---------------------------------------------------------------------------
// qkv_gemm: [1536,256]x[256,2048] per batch, 128x128 tile, BK=64.
// global_load_lds (16B) staging into unpadded XOR-swizzled tiles.
// ---------------------------------------------------------------------------
__global__ __launch_bounds__(256, 2) void qkv_gemm(
    const unsigned short* __restrict__ wq, const unsigned short* __restrict__ xT,
    unsigned short* __restrict__ Qs, unsigned short* __restrict__ Ks,
    unsigned short* __restrict__ Vt) {
  __shared__ unsigned short lds[17408];   // staging: la[128*64], lb[128*64]; epilogue 128*136
  unsigned short* la = lds;
  unsigned short* lb = lds + 8192;
  int o0 = blockIdx.x * 128;
  int n0 = blockIdx.y * 128;
  int b  = blockIdx.z;
  int t  = threadIdx.x;
  int wv = t >> 6, l = t & 63, l15 = l & 15, q = l >> 4;
  int wm = (wv & 1) * 64, wn = (wv >> 1) * 64;
  f32x4 acc[4][4];
#pragma unroll
  for (int i = 0; i < 4; i++)
#pragma unroll
    for (int j = 0; j < 4; j++) acc[i][j] = (f32x4){0.f, 0.f, 0.f, 0.f};
  const unsigned short* Ag = wq + (size_t)o0 * DIMC;
  const unsigned short* Bg = xT + ((size_t)b * SEQ + n0) * DIMC;
  int lrow8 = l >> 3, lcol = l & 7;
  for (int kk = 0; kk < 4; kk++) {
    int k0 = kk * 64;
    __syncthreads();
#pragma unroll
    for (int c0 = 0; c0 < 4; c0++) {
      int c = wv * 4 + c0;                   // 16 chunks of 8 rows x 128B
      int row = c * 8 + lrow8;
      int sg = lcol ^ (row & 7);             // permute GLOBAL col; LDS slot = lane&7
      gld16(Ag + (size_t)row * DIMC + k0 + sg * 8, la + c * 512);
      gld16(Bg + (size_t)row * DIMC + k0 + sg * 8, lb + c * 512);
    }
    __syncthreads();
#pragma unroll
    for (int kh = 0; kh < 2; kh++) {
      bf16x8 af[4], bfr[4];
#pragma unroll
      for (int mt = 0; mt < 4; mt++) {
        int row = wm + mt*16 + l15;
        af[mt] = *(const bf16x8*)(la + row*64 + ((kh*4 + q) ^ (row & 7)) * 8);
      }
#pragma unroll
      for (int nt = 0; nt < 4; nt++) {
        int row = wn + nt*16 + l15;
        bfr[nt] = *(const bf16x8*)(lb + row*64 + ((kh*4 + q) ^ (row & 7)) * 8);
      }
#pragma unroll
      for (int mt = 0; mt < 4; mt++)
#pragma unroll
        for (int nt = 0; nt < 4; nt++)
          acc[mt][nt] = __builtin_amdgcn_mfma_f32_16x16x32_bf16(af[mt], bfr[nt], acc[mt][nt], 0, 0, 0);
    }
  }
  __syncthreads();
  int seg3 = o0 >> 9;            // 0=Q, 1=K, 2=V
  int h0   = (o0 & 511) >> 6;
  if (seg3 == 2) {
#pragma unroll
    for (int mt = 0; mt < 4; mt++)
#pragma unroll
      for (int nt = 0; nt < 4; nt++)
#pragma unroll
        for (int r = 0; r < 4; r++) {
          int ol = wm + mt * 16 + q * 4 + r;
          int h = h0 + (ol >> 6), d = ol & 63;
          int n = n0 + wn + nt * 16 + l15;
          Vt[(((size_t)b * NH + h) * DH + d) * SEQ + n] = f2bf(acc[mt][nt][r]);
        }
  } else {
    unsigned short* dst = (seg3 == 0) ? Qs : Ks;
#pragma unroll
    for (int mt = 0; mt < 4; mt++)
#pragma unroll
      for (int nt = 0; nt < 4; nt++)
#pragma unroll
        for (int r = 0; r < 4; r++) {
          int ol = wm + mt * 16 + q * 4 + r;
          int nn = wn + nt * 16 + l15;
          lds[nn * 136 + ol] = f2bf(acc[mt][nt][r]);
        }
    __syncthreads();
#pragma unroll
    for (int i = 0; i < 8; i++) {
      int idx = i * 256 + t;
      int nn  = idx >> 4;
      int olb = (idx & 15) * 8;
      uint4 v = *(const uint4*)(lds + nn * 136 + olb);
      int h = h0 + (olb >> 6), d = olb & 63;
      *(uint4*)(dst + (((size_t)b * NH + h) * SEQ + n0 + nn) * DH + d) = v;
    }
  }
}

// ---------------------------------------------------------------------------
// attn: 32x32x16 MFMA, M=64 queries/wave, KV-split x2 in-block.
// 256 threads = 4 waves: wave w: cg=w>>1 (key chunk of 1024), qg=w&1 (64 q).
// K/V staged via gld16 into XOR-swizzled LDS tiles (64 keys/iter/chunk).
// P converted D-layout -> A-layout IN REGISTERS (permlane32_swap + bf16 pack)
// -- no P LDS round-trip. Additive partial combine in LDS at the end.
// ---------------------------------------------------------------------------
__global__ __launch_bounds__(256, 2) void attn_kernel(
    const unsigned short* __restrict__ Qs, const unsigned short* __restrict__ Ks,
    const unsigned short* __restrict__ Vt, unsigned short* __restrict__ AO) {
  __shared__ unsigned short KV[16384];  // K0|K1|V0|V1, 4096 shorts (8KB) each
  __shared__ float Lc[256];             // row-sum partials [cg][128 q]
  int n0 = blockIdx.x * 128;
  int bh = blockIdx.y;
  int b = bh >> 3, h = bh & 7;
  int t = threadIdx.x;
  int w = t >> 6, l = t & 63, l31 = l & 31, lh = l >> 5, l7 = l & 7;
  int cg = w >> 1, qg = w & 1;
  // Q B-frags (n=query=l31, k=head-dim) straight from global, once
  const unsigned short* Qg = Qs + ((size_t)bh * SEQ + n0 + qg * 64) * DH;
  bf16x8 qb[2][4];
#pragma unroll
  for (int qt = 0; qt < 2; qt++)
#pragma unroll
    for (int kc = 0; kc < 4; kc++)
      qb[qt][kc] = *(const bf16x8*)(Qg + (qt*32 + l31) * DH + kc*16 + lh*8);
  f32x16 oacc[2][2];
  float lrowp[2] = {0.f, 0.f};
#pragma unroll
  for (int qt = 0; qt < 2; qt++)
#pragma unroll
    for (int dt = 0; dt < 2; dt++)
#pragma unroll
      for (int r = 0; r < 16; r++) oacc[qt][dt][r] = 0.f;
  const unsigned short* Kst = KV + cg * 4096;
  const unsigned short* Vst = KV + 8192 + cg * 4096;
  for (int it = 0; it < 16; it++) {
    int jb = it * 64;
    __syncthreads();                       // previous compute done
    if (w < 2) {                           // stage K for chunk w
      const unsigned short* src = Ks + ((size_t)bh * SEQ + w * 1024 + jb) * DH;
      unsigned short* dst = (unsigned short*)KV + w * 4096;
#pragma unroll
      for (int g = 0; g < 8; g++) {
        int kr = g * 8 + (l >> 3);
        gld16(src + (size_t)kr * DH + (l7 ^ (kr & 7)) * 8, dst + g * 512);
      }
    } else {                               // stage V for chunk w-2
      const unsigned short* src = Vt + (size_t)bh * DH * SEQ + (w - 2) * 1024 + jb;
      unsigned short* dst = (unsigned short*)KV + 8192 + (w - 2) * 4096;
#pragma unroll
      for (int g = 0; g < 8; g++) {
        int dr = g * 8 + (l >> 3);
        gld16(src + (size_t)dr * SEQ + (l7 ^ (dr & 7)) * 8, dst + g * 512);
      }
    }
    __syncthreads();                       // waits vmcnt(0): tiles ready
#pragma unroll
    for (int kb = 0; kb < 64; kb += 32) {  // two 32-key groups
      // S^T = K Q^T : A = K (m=key), B = Q (n=query)
      f32x16 st[2];
#pragma unroll
      for (int qt = 0; qt < 2; qt++)
#pragma unroll
        for (int r = 0; r < 16; r++) st[qt][r] = 0.f;
#pragma unroll
      for (int kc = 0; kc < 4; kc++) {
        bf16x8 kf = *(const bf16x8*)(Kst + (kb + l31) * 64 + (((kc*2 + lh) ^ l7)) * 8);
        st[0] = __builtin_amdgcn_mfma_f32_32x32x16_bf16(kf, qb[0][kc], st[0], 0, 0, 0);
        st[1] = __builtin_amdgcn_mfma_f32_32x32x16_bf16(kf, qb[1][kc], st[1], 0, 0, 0);
      }
      // V B-frags (n=d, k=key), shared across q-tiles
      bf16x8 vf[2][2];
#pragma unroll
      for (int kc2 = 0; kc2 < 2; kc2++)
#pragma unroll
        for (int dt = 0; dt < 2; dt++)
          vf[kc2][dt] = *(const bf16x8*)(Vst + (dt*32 + l31) * 64 +
                                         ((((kb >> 3) + kc2*2 + lh) ^ l7)) * 8);
#pragma unroll
      for (int qt = 0; qt < 2; qt++) {
        // p = exp2(s); row-sum partial (col=query=l31 per lane)
        float p[16];
        float s0 = 0.f;
#pragma unroll
        for (int r = 0; r < 16; r++) { p[r] = __builtin_amdgcn_exp2f(st[qt][r]); s0 += p[r]; }
        lrowp[qt] += s0;
        // D-layout -> A-layout in registers: for each key-16 chunk hf,
        // regs hf*8+j hold keys {j (lo lanes), j+4 (hi)}, regs hf*8+4+j keys {j+8, j+12}.
        // swap32 gives x'={key j lo, key j+8 hi}, y'={key j+4 lo, key j+12 hi}.
        bf16x8 af[2];
#pragma unroll
        for (int hf = 0; hf < 2; hf++) {
          uint32_t xs[4], ys[4];
#pragma unroll
          for (int j = 0; j < 4; j++) {
            xs[j] = fbits(p[hf*8 + j]);
            ys[j] = fbits(p[hf*8 + 4 + j]);
            swap32(xs[j], ys[j]);
          }
          uint32_t d0 = pku(xs[0], xs[1]);
          uint32_t d1 = pku(xs[2], xs[3]);
          uint32_t d2 = pku(ys[0], ys[1]);
          uint32_t d3 = pku(ys[2], ys[3]);
          union { uint32_t u[4]; bf16x8 v; } cv;
          cv.u[0] = d0; cv.u[1] = d1; cv.u[2] = d2; cv.u[3] = d3;
          af[hf] = cv.v;
        }
#pragma unroll
        for (int kc2 = 0; kc2 < 2; kc2++)
#pragma unroll
          for (int dt = 0; dt < 2; dt++)
            oacc[qt][dt] = __builtin_amdgcn_mfma_f32_32x32x16_bf16(af[kc2], vf[kc2][dt], oacc[qt][dt], 0, 0, 0);
      }
    }
  }
  // ---- combine the two kv-chunks (purely additive; no max-rescale) ----
#pragma unroll
  for (int qt = 0; qt < 2; qt++) {
    float v = lrowp[qt];
    v += __shfl_xor(v, 32);                // lo/hi halves hold disjoint keys
    if (l < 32) Lc[cg * 128 + qg * 64 + qt * 32 + l31] = v;
  }
  __syncthreads();
  float* Oc = (float*)KV;                  // [128 q][64 d] fp32 = 32 KB
  if (cg == 1) {
#pragma unroll
    for (int qt = 0; qt < 2; qt++)
#pragma unroll
      for (int dt = 0; dt < 2; dt++)
#pragma unroll
        for (int r = 0; r < 16; r++) {
          int qrow = qg*64 + qt*32 + (r & 3) + 8*(r >> 2) + 4*lh;
          Oc[qrow * 64 + dt*32 + l31] = oacc[qt][dt][r];
        }
  }
  __syncthreads();
  if (cg == 0) {
    unsigned short* AOb = AO + (size_t)b * SEQ * HID + h * DH;
#pragma unroll
    for (int qt = 0; qt < 2; qt++)
#pragma unroll
      for (int r = 0; r < 16; r++) {
        int qrow = qg*64 + qt*32 + (r & 3) + 8*(r >> 2) + 4*lh;
        float inv = __builtin_amdgcn_rcpf(Lc[qrow] + Lc[128 + qrow]);
        int n = n0 + qrow;
#pragma unroll
        for (int dt = 0; dt < 2; dt++) {
          float val = (oacc[qt][dt][r] + Oc[qrow * 64 + dt*32 + l31]) * inv;
          AOb[(size_t)n * HID + dt*32 + l31] = f2bf(val);
        }
      }
  }
}

// ---------------------------------------------------------------------------
// out_gemm: [256,512] x AO^T -> out[b][256][2048] fp32 + bias
// global_load_lds staging, XOR-swizzled tiles.
// ---------------------------------------------------------------------------
__global__ __launch_bounds__(256, 2) void out_gemm(
    const unsigned short* __restrict__ wo, const unsigned short* __restrict__ AO,
    const float* __restrict__ bias, float* __restrict__ out) {
  __shared__ unsigned short la[64 * 64];
  __shared__ unsigned short lb[128 * 64];
  int o0 = blockIdx.x * 64;
  int n0 = blockIdx.y * 128;
  int b  = blockIdx.z;
  int t  = threadIdx.x;
  int wv = t >> 6, l = t & 63, l15 = l & 15, q = l >> 4;
  int wm = (wv & 1) * 32, wn = (wv >> 1) * 64;
  f32x4 acc[2][4];
#pragma unroll
  for (int i = 0; i < 2; i++)
#pragma unroll
    for (int j = 0; j < 4; j++) acc[i][j] = (f32x4){0.f,0.f,0.f,0.f};
  const unsigned short* Ag = wo + (size_t)o0 * HID;
  const unsigned short* Bg = AO + ((size_t)b * SEQ + n0) * HID;
  int lrow8 = l >> 3, lcol = l & 7;
  for (int kk = 0; kk < 8; kk++) {
    int k0 = kk * 64;
    __syncthreads();
#pragma unroll
    for (int c0 = 0; c0 < 2; c0++) {       // A: 8 chunks
      int c = wv * 2 + c0;
      int row = c * 8 + lrow8;
      int sg = lcol ^ (row & 7);
      gld16(Ag + (size_t)row * HID + k0 + sg * 8, la + c * 512);
    }
#pragma unroll
    for (int c0 = 0; c0 < 4; c0++) {       // B: 16 chunks
      int c = wv * 4 + c0;
      int row = c * 8 + lrow8;
      int sg = lcol ^ (row & 7);
      gld16(Bg + (size_t)row * HID + k0 + sg * 8, lb + c * 512);
    }
    __syncthreads();
#pragma unroll
    for (int kh = 0; kh < 2; kh++) {
      bf16x8 af[2], bfr[4];
#pragma unroll
      for (int mt = 0; mt < 2; mt++) {
        int row = wm + mt*16 + l15;
        af[mt] = *(const bf16x8*)(la + row*64 + ((kh*4 + q) ^ (row & 7)) * 8);
      }
#pragma unroll
      for (int nt = 0; nt < 4; nt++) {
        int row = wn + nt*16 + l15;
        bfr[nt] = *(const bf16x8*)(lb + row*64 + ((kh*4 + q) ^ (row & 7)) * 8);
      }
#pragma unroll
      for (int mt = 0; mt < 2; mt++)
#pragma unroll
        for (int nt = 0; nt < 4; nt++)
          acc[mt][nt] = __builtin_amdgcn_mfma_f32_16x16x32_bf16(af[mt], bfr[nt], acc[mt][nt], 0,0,0);
    }
  }
#pragma unroll
  for (int mt = 0; mt < 2; mt++)
#pragma unroll
    for (int nt = 0; nt < 4; nt++)
#pragma unroll
      for (int r = 0; r < 4; r++) {
        int o2 = o0 + wm + mt*16 + q*4 + r;
        int n  = n0 + wn + nt*16 + l15;
        out[((size_t)b * DIMC + o2) * SEQ + n] = acc[mt][nt][r] + bias[o2];
      }
}

extern "C" void kernel_launch(void* const* d_in, const int* in_sizes, int n_in,
                              void* d_out, int out_size, void* d_ws, size_t ws_size,
                              hipStream_t stream) {
  const float* x    = (const float*)d_in[0];
  const float* wqkv = (const float*)d_in[1];
  const float* wout = (const float*)d_in[2];
  const float* bout = (const float*)d_in[3];
  float* out = (float*)d_out;
  char* ws = (char*)d_ws;
  unsigned short* wqkv_b = (unsigned short*)(ws);
  unsigned short* wout_b = (unsigned short*)(ws + 786432);
  unsigned short* xT     = (unsigned short*)(ws + 1048576);
  unsigned short* Qs     = (unsigned short*)(ws + 5242880);
  unsigned short* Ks     = (unsigned short*)(ws + 13631488);
  unsigned short* Vt     = (unsigned short*)(ws + 22020096);
  unsigned short* AO     = (unsigned short*)(ws + 30408704);
  prep_kernel<<<1024, 256, 0, stream>>>(x, wqkv, wout, wqkv_b, wout_b, xT);
  qkv_gemm<<<dim3(12, 16, 4), 256, 0, stream>>>(wqkv_b, xT, Qs, Ks, Vt);
  attn_kernel<<<dim3(16, 32), 256, 0, stream>>>(Qs, Ks, Vt, AO);
  out_gemm<<<dim3(4, 16, 4), 256, 0, stream>>>(wout_b, AO, bout, out);
}